// Round 10
// baseline (229.930 us; speedup 1.0000x reference)
//
#include <hip/hip_runtime.h>

#define S_LEN 2048
#define NH 16
#define DH 64
#define DM 1024
#define M_TOK 8192              // B*S
#define SZX ((size_t)M_TOK * DM)   // 8 Mi elems
#define SZW ((size_t)DM * DM)      // 1 Mi elems (2^20)

typedef unsigned short u16;
typedef unsigned int u32;
typedef __attribute__((ext_vector_type(8))) short bf16x8;   // 8 bf16 = 4 VGPRs
typedef __attribute__((ext_vector_type(4))) float f32x4;

// round-half-up bf16 (error bound == RNE except exact ties)
__device__ __forceinline__ u16 f2bf(float f) {
  union { float f; u32 u; } v; v.f = f;
  return (u16)((v.u + 0x8000u) >> 16);
}
// pack two floats -> (bf16(y)<<16)|bf16(x) in 2 adds + 1 v_perm
__device__ __forceinline__ u32 pack_bf2(float x, float y) {
  union { float f; u32 u; } a, b; a.f = x; b.f = y;
  return __builtin_amdgcn_perm(b.u + 0x8000u, a.u + 0x8000u, 0x07060302u);
}
__device__ __forceinline__ float fast_exp2(float x) {
  float r; asm("v_exp_f32 %0, %1" : "=v"(r) : "v"(x)); return r;
}
// async global->LDS, 16B/lane. dest = wave-uniform base + lane*16.
__device__ __forceinline__ void gload16(const u16* g, u16* l) {
  __builtin_amdgcn_global_load_lds((const __attribute__((address_space(1))) void*)g,
                                   (__attribute__((address_space(3))) void*)l,
                                   16, 0, 0);
}

#define QSCALE 0.18033688f   // 1/sqrt(64) * log2(e)

// Fused cast: X (8Mi) + Wq|Wk|Wv|Wo (4 x 1Mi) -> contiguous bf16 dst.
__global__ __launch_bounds__(256) void cast_all(const float* __restrict__ X,
                                                const float* __restrict__ q,
                                                const float* __restrict__ k,
                                                const float* __restrict__ v,
                                                const float* __restrict__ o,
                                                u16* __restrict__ dst) {
  const int i = (blockIdx.x * 256 + threadIdx.x) * 8;   // [0, 12Mi)
  const float* src;
  int local;
  if (i < (int)SZX) { src = X; local = i; }
  else {
    const int j = i - (int)SZX;
    const int region = j >> 20;
    src = (region == 0) ? q : (region == 1) ? k : (region == 2) ? v : o;
    local = j & ((1 << 20) - 1);
  }
  const float4 a = *(const float4*)(src + local);
  const float4 b = *(const float4*)(src + local + 4);
  uint4 r;
  r.x = pack_bf2(a.x, a.y); r.y = pack_bf2(a.z, a.w);
  r.z = pack_bf2(b.x, b.y); r.w = pack_bf2(b.z, b.w);
  *(uint4*)(dst + i) = r;
}

// ---------------------------------------------------------------------------
// 128x128-tile GEMM, C[m,n] = sum_k A[m,k]*B[n,k], K = 1024, BK = 64.
// r15: OPERAND-SWAP epilogue vectorization. r6 counters: QKV gemm = 70.4us,
// MfmaUtil 30 / VALUBusy 24 / HBM 18% -- no pipe saturated; the extra cost
// vs the clean m97 kernel is the scatter epilogue (64 scalar 2B stores per
// thread for Q/K: fragment rows run along m=s while memory is contiguous
// along n=dh). Swapping the MFMA operands (mfma(bf,af)) transposes the
// fragment (first operand takes the reg side -- proven in-codebase by attn's
// mfma(kf,qf) giving col=q), so each lane holds 4 CONSECUTIVE dh -> Q/K
// store uint2 (16 stores/thread, was 64) and MODE 1 stores float4.
// V^T keeps the original order (its uint2-along-s path is already ideal).
// which = n_blk>>10 is block-uniform -> uniform branch, two instantiations.
// Same dot products, bit-identical values; only store grouping changes.
// (r7/r8/r9 were GPUAcquisitionTimeouts; identical kernel resubmitted.)
// ---------------------------------------------------------------------------
template<int MODE, bool SW>
__device__ __forceinline__ void gemm_body(const u16* __restrict__ A,
                                          const u16* __restrict__ Bw,
                                          void* __restrict__ Cv,
                                          u16* __restrict__ As,
                                          u16* __restrict__ Bs) {
  const int tid = threadIdx.x;
  const int lane = tid & 63;
  const int wave = tid >> 6;
  const int col = lane & 15, quad = lane >> 4;
  const int wm = (wave & 1) * 64, wn = (wave >> 1) * 64;
  const int m_blk = blockIdx.x * 128, n_blk = blockIdx.y * 128;

  const int srow = tid >> 3;
  const int skg = (tid & 7) ^ (srow & 7);
  const u16* Ag = A + (size_t)(m_blk + srow) * DM + skg * 8;
  const u16* Bg = Bw + (size_t)(n_blk + srow) * DM + skg * 8;

  f32x4 acc[4][4];
#pragma unroll
  for (int i = 0; i < 4; ++i)
#pragma unroll
    for (int j = 0; j < 4; ++j) acc[i][j] = (f32x4){0.f, 0.f, 0.f, 0.f};

  const int c0 = (quad ^ (col & 7)) * 8;   // k-group quad
  const int c1 = c0 ^ 32;                  // k-group quad+4

  for (int k0 = 0; k0 < DM; k0 += 64) {
#pragma unroll
    for (int i = 0; i < 4; ++i) {
      gload16(Ag + (size_t)(32 * i) * DM + k0, &As[tid * 8 + i * 2048]);
      gload16(Bg + (size_t)(32 * i) * DM + k0, &Bs[tid * 8 + i * 2048]);
    }
    __syncthreads();
    bf16x8 af[4], bf[4];
#pragma unroll
    for (int i = 0; i < 4; ++i)
      af[i] = *(const bf16x8*)&As[(wm + i * 16 + col) * 64 + c0];
#pragma unroll
    for (int j = 0; j < 4; ++j)
      bf[j] = *(const bf16x8*)&Bs[(wn + j * 16 + col) * 64 + c0];
#pragma unroll
    for (int i = 0; i < 4; ++i)
#pragma unroll
      for (int j = 0; j < 4; ++j)
        acc[i][j] = SW
          ? __builtin_amdgcn_mfma_f32_16x16x32_bf16(bf[j], af[i], acc[i][j], 0, 0, 0)
          : __builtin_amdgcn_mfma_f32_16x16x32_bf16(af[i], bf[j], acc[i][j], 0, 0, 0);
#pragma unroll
    for (int i = 0; i < 4; ++i)
      af[i] = *(const bf16x8*)&As[(wm + i * 16 + col) * 64 + c1];
#pragma unroll
    for (int j = 0; j < 4; ++j)
      bf[j] = *(const bf16x8*)&Bs[(wn + j * 16 + col) * 64 + c1];
#pragma unroll
    for (int i = 0; i < 4; ++i)
#pragma unroll
      for (int j = 0; j < 4; ++j)
        acc[i][j] = SW
          ? __builtin_amdgcn_mfma_f32_16x16x32_bf16(bf[j], af[i], acc[i][j], 0, 0, 0)
          : __builtin_amdgcn_mfma_f32_16x16x32_bf16(af[i], bf[j], acc[i][j], 0, 0, 0);
    __syncthreads();
  }

  // epilogue.
  if (MODE == 0 && SW) {
    // Q/K, swapped frags: reg r -> n = n_blk+wn+j*16+quad*4+r (4 consecutive
    // dh, one head per wave); col -> m = s. One uint2 store per acc.
    const int which = n_blk >> 10;            // 0=Q 1=K (uniform per block)
    const float sc = (which == 0) ? QSCALE : 1.0f;
    u16* dst = (u16*)Cv + (size_t)which * SZX;
    const int h = ((n_blk + wn) & 1023) >> 6; // uniform per wave
#pragma unroll
    for (int i = 0; i < 4; ++i) {
      const int m = m_blk + wm + i * 16 + col;
      const int b = m >> 11, s = m & 2047;
      const size_t rowb = ((size_t)(b * NH + h) * S_LEN + s) * DH;
#pragma unroll
      for (int j = 0; j < 4; ++j) {
        const int dh0 = j * 16 + quad * 4;
        uint2 pk;
        pk.x = pack_bf2(acc[i][j][0] * sc, acc[i][j][1] * sc);
        pk.y = pack_bf2(acc[i][j][2] * sc, acc[i][j][3] * sc);
        *(uint2*)&dst[rowb + dh0] = pk;
      }
    }
  } else if (MODE == 0) {
    // V^T [bh][dh][s]: unswapped, reg r -> m = s (4 consecutive), uint2.
#pragma unroll
    for (int i = 0; i < 4; ++i) {
#pragma unroll
      for (int j = 0; j < 4; ++j) {
        const int n = n_blk + wn + j * 16 + col;
        const int nn = n & 1023;
        const int h = nn >> 6, dh = nn & 63;
        u16* dst = (u16*)Cv + (size_t)2 * SZX;
        const int m0 = m_blk + wm + i * 16 + quad * 4;
        const int b = m0 >> 11;
        uint2 pk;
        pk.x = pack_bf2(acc[i][j][0], acc[i][j][1]);
        pk.y = pack_bf2(acc[i][j][2], acc[i][j][3]);
        *(uint2*)&dst[((size_t)((b * NH + h) * DH + dh)) * S_LEN + (m0 & 2047)] = pk;
      }
    }
  } else {
    // MODE 1, swapped: reg r -> n (4 consecutive), float4 store per acc.
#pragma unroll
    for (int i = 0; i < 4; ++i) {
      const int m = m_blk + wm + i * 16 + col;
#pragma unroll
      for (int j = 0; j < 4; ++j) {
        const int n0 = n_blk + wn + j * 16 + quad * 4;
        float4 v;
        v.x = acc[i][j][0]; v.y = acc[i][j][1];
        v.z = acc[i][j][2]; v.w = acc[i][j][3];
        *(float4*)&((float*)Cv)[(size_t)m * DM + n0] = v;
      }
    }
  }
}

template<int MODE>
__global__ __launch_bounds__(256) void gemm128(const u16* __restrict__ A,
                                               const u16* __restrict__ Bw,
                                               void* __restrict__ Cv) {
  __shared__ __align__(16) u16 As[128 * 64];
  __shared__ __align__(16) u16 Bs[128 * 64];
  if (MODE == 0) {
    if ((blockIdx.y * 128) >> 10 == 2) gemm_body<0, false>(A, Bw, Cv, As, Bs);
    else                               gemm_body<0, true >(A, Bw, Cv, As, Bs);
  } else {
    gemm_body<1, true>(A, Bw, Cv, As, Bs);
  }
}

// ---------------------------------------------------------------------------
// Flash attention, causal, S^T form, dbuf K/V, no online max. (r14, verified:
// adjacent pairing, shared-V merged step, 2-tile barrier windows, balanced
// 512x34-step blocks.) Unchanged this round.
// ---------------------------------------------------------------------------
template<bool DIAG_L>
__device__ __forceinline__ void stepM(const u16* __restrict__ Ksb,
                                      const u16* __restrict__ Vsb,
                                      u16* __restrict__ Pw,
                                      bf16x8 qH0, bf16x8 qH1,
                                      bf16x8 qL0, bf16x8 qL1,
                                      f32x4& lH, f32x4* oH,
                                      f32x4& lL, f32x4* oL,
                                      f32x4 zero4, bf16x8 ones,
                                      int c0, int c1, int col, int quad,
                                      int q_l) {
  const int colc = col & 7;
  f32x4 sH[4], sL[4];
#pragma unroll
  for (int t = 0; t < 4; ++t) {
    const int row = (t * 16 + col) * 64;
    const bf16x8 kf0 = *(const bf16x8*)&Ksb[row + c0];
    const bf16x8 kf1 = *(const bf16x8*)&Ksb[row + c1];
    f32x4 z = __builtin_amdgcn_mfma_f32_16x16x32_bf16(kf0, qH0, zero4, 0, 0, 0);
    sH[t] = __builtin_amdgcn_mfma_f32_16x16x32_bf16(kf1, qH1, z, 0, 0, 0);
    f32x4 y = __builtin_amdgcn_mfma_f32_16x16x32_bf16(kf0, qL0, zero4, 0, 0, 0);
    sL[t] = __builtin_amdgcn_mfma_f32_16x16x32_bf16(kf1, qL1, y, 0, 0, 0);
  }
  // mask + exp (both strips)
#pragma unroll
  for (int t = 0; t < 4; ++t)
#pragma unroll
    for (int r = 0; r < 4; ++r) {
      sH[t][r] = fast_exp2(sH[t][r]);
      if (DIAG_L && (t * 16 + quad * 4 + r) > q_l) sL[t][r] = -1e30f;
      sL[t][r] = fast_exp2(sL[t][r]);
    }
  // ---- P_H round trip ----
#pragma unroll
  for (int t = 0; t < 4; ++t) {
    uint2 pk;
    pk.x = pack_bf2(sH[t][0], sH[t][1]);
    pk.y = pack_bf2(sH[t][2], sH[t][3]);
    const int pg = (((t * 2) + (quad >> 1)) ^ colc) * 8 + (quad & 1) * 4;
    *(uint2*)&Pw[col * 64 + pg] = pk;
  }
  const bf16x8 pfH0 = *(const bf16x8*)&Pw[col * 64 + ((quad ^ colc) * 8)];
  const bf16x8 pfH1 = *(const bf16x8*)&Pw[col * 64 + (((4 + quad) ^ colc) * 8)];
  // ---- P_L round trip (same buffer; in-wave DS order protects H reads) ----
#pragma unroll
  for (int t = 0; t < 4; ++t) {
    uint2 pk;
    pk.x = pack_bf2(sL[t][0], sL[t][1]);
    pk.y = pack_bf2(sL[t][2], sL[t][3]);
    const int pg = (((t * 2) + (quad >> 1)) ^ colc) * 8 + (quad & 1) * 4;
    *(uint2*)&Pw[col * 64 + pg] = pk;
  }
  const bf16x8 pfL0 = *(const bf16x8*)&Pw[col * 64 + ((quad ^ colc) * 8)];
  const bf16x8 pfL1 = *(const bf16x8*)&Pw[col * 64 + (((4 + quad) ^ colc) * 8)];
  // ---- l for both strips ----
  lH = __builtin_amdgcn_mfma_f32_16x16x32_bf16(ones, pfH0, lH, 0, 0, 0);
  lH = __builtin_amdgcn_mfma_f32_16x16x32_bf16(ones, pfH1, lH, 0, 0, 0);
  lL = __builtin_amdgcn_mfma_f32_16x16x32_bf16(ones, pfL0, lL, 0, 0, 0);
  lL = __builtin_amdgcn_mfma_f32_16x16x32_bf16(ones, pfL1, lL, 0, 0, 0);
  // ---- shared-V PV: one V pass feeds both strips ----
#pragma unroll
  for (int t = 0; t < 4; ++t) {
    const int row = (t * 16 + col) * 64;
    const bf16x8 vf0 = *(const bf16x8*)&Vsb[row + c0];
    const bf16x8 vf1 = *(const bf16x8*)&Vsb[row + c1];
    oH[t] = __builtin_amdgcn_mfma_f32_16x16x32_bf16(vf0, pfH0, oH[t], 0, 0, 0);
    oH[t] = __builtin_amdgcn_mfma_f32_16x16x32_bf16(vf1, pfH1, oH[t], 0, 0, 0);
    oL[t] = __builtin_amdgcn_mfma_f32_16x16x32_bf16(vf0, pfL0, oL[t], 0, 0, 0);
    oL[t] = __builtin_amdgcn_mfma_f32_16x16x32_bf16(vf1, pfL1, oL[t], 0, 0, 0);
  }
}

// single-strip (H) step, used only for the H-diagonal tail of each pair.
template<bool DIAG_H>
__device__ __forceinline__ void stepS(const u16* __restrict__ Ksb,
                                      const u16* __restrict__ Vsb,
                                      u16* __restrict__ Pw,
                                      bf16x8 qH0, bf16x8 qH1,
                                      f32x4& lH, f32x4* oH,
                                      f32x4 zero4, bf16x8 ones,
                                      int c0, int c1, int col, int quad,
                                      int q_l) {
  const int colc = col & 7;
  f32x4 sH[4];
#pragma unroll
  for (int t = 0; t < 4; ++t) {
    const int row = (t * 16 + col) * 64;
    const bf16x8 kf0 = *(const bf16x8*)&Ksb[row + c0];
    const bf16x8 kf1 = *(const bf16x8*)&Ksb[row + c1];
    f32x4 z = __builtin_amdgcn_mfma_f32_16x16x32_bf16(kf0, qH0, zero4, 0, 0, 0);
    sH[t] = __builtin_amdgcn_mfma_f32_16x16x32_bf16(kf1, qH1, z, 0, 0, 0);
  }
#pragma unroll
  for (int t = 0; t < 4; ++t)
#pragma unroll
    for (int r = 0; r < 4; ++r) {
      if (DIAG_H && (t * 16 + quad * 4 + r) > q_l) sH[t][r] = -1e30f;
      sH[t][r] = fast_exp2(sH[t][r]);
    }
#pragma unroll
  for (int t = 0; t < 4; ++t) {
    uint2 pk;
    pk.x = pack_bf2(sH[t][0], sH[t][1]);
    pk.y = pack_bf2(sH[t][2], sH[t][3]);
    const int pg = (((t * 2) + (quad >> 1)) ^ colc) * 8 + (quad & 1) * 4;
    *(uint2*)&Pw[col * 64 + pg] = pk;
  }
  const bf16x8 pf0 = *(const bf16x8*)&Pw[col * 64 + ((quad ^ colc) * 8)];
  const bf16x8 pf1 = *(const bf16x8*)&Pw[col * 64 + (((4 + quad) ^ colc) * 8)];
  lH = __builtin_amdgcn_mfma_f32_16x16x32_bf16(ones, pf0, lH, 0, 0, 0);
  lH = __builtin_amdgcn_mfma_f32_16x16x32_bf16(ones, pf1, lH, 0, 0, 0);
#pragma unroll
  for (int t = 0; t < 4; ++t) {
    const int row = (t * 16 + col) * 64;
    const bf16x8 vf0 = *(const bf16x8*)&Vsb[row + c0];
    const bf16x8 vf1 = *(const bf16x8*)&Vsb[row + c1];
    oH[t] = __builtin_amdgcn_mfma_f32_16x16x32_bf16(vf0, pf0, oH[t], 0, 0, 0);
    oH[t] = __builtin_amdgcn_mfma_f32_16x16x32_bf16(vf1, pf1, oH[t], 0, 0, 0);
  }
}

__global__ __launch_bounds__(256) void attn_kernel(const u16* __restrict__ Qg,
                                                   const u16* __restrict__ Kg,
                                                   const u16* __restrict__ Vtg,
                                                   u16* __restrict__ AO) {
  __shared__ __align__(16) u16 Ks[2][2][64 * 64];  // dbuf x 2 tiles, swizzled
  __shared__ __align__(16) u16 Vs[2][2][64 * 64];  // dbuf x 2 tiles, swizzled
  __shared__ __align__(16) u16 Ps[4][16 * 64];     // per-wave, XOR-swizzled

  const int id = blockIdx.x;                    // 0..511
  const int bh = ((id & 7) << 3) | (id >> 6);   // 0..63 (id&7 = XCD colocate)
  const int slot = (id >> 3) & 7;               // 0..7
  const int tid = threadIdx.x, lane = tid & 63, wave = tid >> 6;
  const int col = lane & 15, quad = lane >> 4;

  const u16* Qb = Qg + (size_t)bh * S_LEN * DH;
  const u16* Kb = Kg + (size_t)bh * S_LEN * DH;
  const u16* Vb = Vtg + (size_t)bh * DH * S_LEN;

  const f32x4 zero4 = (f32x4){0.f, 0.f, 0.f, 0.f};
  const bf16x8 ones = (bf16x8){0x3F80, 0x3F80, 0x3F80, 0x3F80,
                               0x3F80, 0x3F80, 0x3F80, 0x3F80};   // bf16 1.0

  // staging granules: row = g>>3, slot = g&7, source grp = slot^(row&7).
  const int sr0 = tid >> 3;
  const int sk0 = (tid & 7) ^ (sr0 & 7);
  const u16* K0 = Kb + (size_t)sr0 * DH + sk0 * 8;
  const u16* K1 = Kb + (size_t)(sr0 + 32) * DH + sk0 * 8;
  const u16* V0 = Vb + (size_t)sr0 * S_LEN + sk0 * 8;
  const u16* V1 = Vb + (size_t)(sr0 + 32) * S_LEN + sk0 * 8;

  const int c0 = (quad ^ (col & 7)) * 8;
  const int c1 = c0 ^ 32;
  const int q_l = wave * 16 + col;
  u16* Pw = &Ps[wave][0];
  const int b = bh >> 4, h = bh & 15;

  // window w covers kv tiles 2w and 2w+1 (128 rows), staged into dbuf nb.
#define STAGEW(w, nb) do {                                            \
    gload16(K0 + (size_t)(2 * (w)) * 64 * DH,     &Ks[nb][0][tid * 8]);        \
    gload16(K1 + (size_t)(2 * (w)) * 64 * DH,     &Ks[nb][0][2048 + tid * 8]); \
    gload16(K0 + (size_t)(2 * (w) + 1) * 64 * DH, &Ks[nb][1][tid * 8]);        \
    gload16(K1 + (size_t)(2 * (w) + 1) * 64 * DH, &Ks[nb][1][2048 + tid * 8]); \
    gload16(V0 + (2 * (w)) * 64,                  &Vs[nb][0][tid * 8]);        \
    gload16(V1 + (2 * (w)) * 64,                  &Vs[nb][0][2048 + tid * 8]); \
    gload16(V0 + (2 * (w) + 1) * 64,              &Vs[nb][1][tid * 8]);        \
    gload16(V1 + (2 * (w) + 1) * 64,              &Vs[nb][1][2048 + tid * 8]); \
  } while (0)

  for (int pi = 0; pi < 2; ++pi) {
    const int p = pi ? slot : (15 - slot);      // long pair first
    const int qtH = 2 * p + 1;

    // Q B-frags: n = q = col, k = dh = quad*8+j (+32); qtL row = qtH row - 64
    const u16* qrowH = Qb + (size_t)(qtH * 64 + wave * 16 + col) * DH + quad * 8;
    const bf16x8 qH0 = *(const bf16x8*)(qrowH);
    const bf16x8 qH1 = *(const bf16x8*)(qrowH + 32);
    const bf16x8 qL0 = *(const bf16x8*)(qrowH - 64 * DH);
    const bf16x8 qL1 = *(const bf16x8*)(qrowH - 64 * DH + 32);

    f32x4 lH = zero4, lL = zero4;
    f32x4 oH[4], oL[4];
#pragma unroll
    for (int t = 0; t < 4; ++t) { oH[t] = zero4; oL[t] = zero4; }

    // restage guard (pair B: prior pair's last reads must retire first)
    __syncthreads();
    STAGEW(0, 0);

    // full windows w = 0..p-1 (tiles 2w, 2w+1 fully visible to both strips)
    for (int w = 0; w < p; ++w) {
      __syncthreads();
      STAGEW(w + 1, (w + 1) & 1);
      stepM<false>(&Ks[w & 1][0][0], &Vs[w & 1][0][0], Pw,
                   qH0, qH1, qL0, qL1, lH, oH, lL, oL,
                   zero4, ones, c0, c1, col, quad, q_l);
      stepM<false>(&Ks[w & 1][1][0], &Vs[w & 1][1][0], Pw,
                   qH0, qH1, qL0, qL1, lH, oH, lL, oL,
                   zero4, ones, c0, c1, col, quad, q_l);
    }
    // final window w == p: tile 2p = L-diagonal (merged), tile 2p+1 =
    // H-diagonal (single strip; L's extent ended at 2p).
    {
      __syncthreads();
      stepM<true>(&Ks[p & 1][0][0], &Vs[p & 1][0][0], Pw,
                  qH0, qH1, qL0, qL1, lH, oH, lL, oL,
                  zero4, ones, c0, c1, col, quad, q_l);
      stepS<true>(&Ks[p & 1][1][0], &Vs[p & 1][1][0], Pw,
                  qH0, qH1, lH, oH, zero4, ones, c0, c1, col, quad, q_l);
    }

    // epilogue: l[0] holds the full l for this lane's q = q_l.
    {
      const float inv = __builtin_amdgcn_rcpf(lH[0]);
      const size_t base = (size_t)(b * S_LEN + qtH * 64 + q_l) * DM + h * DH;
#pragma unroll
      for (int t = 0; t < 4; ++t) {
        uint2 pk;
        pk.x = pack_bf2(oH[t][0] * inv, oH[t][1] * inv);
        pk.y = pack_bf2(oH[t][2] * inv, oH[t][3] * inv);
        *(uint2*)&AO[base + t * 16 + quad * 4] = pk;
      }
    }
    {
      const float inv = __builtin_amdgcn_rcpf(lL[0]);
      const size_t base = (size_t)(b * S_LEN + (qtH - 1) * 64 + q_l) * DM + h * DH;
#pragma unroll
      for (int t = 0; t < 4; ++t) {
        uint2 pk;
        pk.x = pack_bf2(oL[t][0] * inv, oL[t][1] * inv);
        pk.y = pack_bf2(oL[t][2] * inv, oL[t][3] * inv);
        *(uint2*)&AO[base + t * 16 + quad * 4] = pk;
      }
    }
  }
#undef STAGEW
}

extern "C" void kernel_launch(void* const* d_in, const int* in_sizes, int n_in,
                              void* d_out, int out_size, void* d_ws, size_t ws_size,
                              hipStream_t stream) {
  const float* X  = (const float*)d_in[0];
  const float* Wq = (const float*)d_in[1];
  const float* Wk = (const float*)d_in[2];
  const float* Wv = (const float*)d_in[3];
  const float* Wo = (const float*)d_in[4];

  u16* Xb   = (u16*)d_ws;            // 8Mi  (reused as AO after QKV)
  u16* Wqkv = Xb + SZX;              // 3Mi  (Wq|Wk|Wv contiguous)
  u16* Wob  = Wqkv + 3 * SZW;        // 1Mi  (contiguous after Wqkv)
  u16* Qb   = Wob + SZW;             // 8Mi  [bh][s][dh], pre-scaled QSCALE
  u16* Kb   = Qb + SZX;              // 8Mi  [bh][s][dh]
  u16* VT   = Kb + SZX;              // 8Mi  [bh][dh][s]
  u16* AO   = Xb;

  cast_all<<<(int)((SZX + 4 * SZW) / 8 / 256), 256, 0, stream>>>(X, Wq, Wk, Wv, Wo, Xb);

  gemm128<0><<<dim3(M_TOK / 128, 3 * DM / 128), 256, 0, stream>>>(Xb, Wqkv, Qb);

  attn_kernel<<<dim3(512), 256, 0, stream>>>(Qb, Kb, VT, AO);

  gemm128<1><<<dim3(M_TOK / 128, DM / 128), 256, 0, stream>>>(AO, Wob, d_out);
}